// Round 9
// baseline (1277.470 us; speedup 1.0000x reference)
//
#include <hip/hip_runtime.h>
#include <hip/hip_bf16.h>
#include <hip/hip_fp16.h>

#define N_NODES   100000
#define N_FEAT    512
#define HIDDEN    64
#define N_CLASSES 40
#define KITER     10
#define ALPHA     0.1f
#define HPITCH    72      // LDS h pitch in halves (144 B) to break bank conflicts
#define NXCD      8
#define WIN       (N_NODES / NXCD)    // 12500 dst nodes per window
#define NPH       4                   // src phases
#define SRCWIN    (N_NODES / NPH)     // 25000 src nodes -> 2 MB packed rows, L2-fit
#define SUBCAP    131072              // per-(dstwin,srcphase) cap (exp. 100K)
#define PARTB     2048                // partition blocks
#define CAP       128                 // LDS bucket capacity per (dstwin,srcphase) (exp. 49)
#define N40       ((size_t)N_NODES * 40)

typedef __attribute__((ext_vector_type(8))) short bf16x8;
typedef __attribute__((ext_vector_type(4))) float f32x4;

__device__ __forceinline__ float bf2f(unsigned short u) {
    union { unsigned int i; float f; } c;
    c.i = ((unsigned int)u) << 16;
    return c.f;
}
__device__ __forceinline__ unsigned short f2bf(float f) {
    union { float f; unsigned int u; } c; c.f = f;
    unsigned int r = c.u + 0x7FFFu + ((c.u >> 16) & 1u);   // RNE
    return (unsigned short)(r >> 16);
}

// ---------------- setup / dtype detection ----------------
__global__ void zero_cur_kernel(int* __restrict__ cur, int* __restrict__ flags) {
    int t = threadIdx.x;
    if (t < 33) cur[t] = 0;    // 32 sub-bucket cursors + 1 overflow cursor
    if (t >= 33 && t < 35) flags[t - 33] = 0;
}

__global__ void detect_float_kernel(const unsigned short* __restrict__ w1raw,
                                    int* __restrict__ flags) {
    int i = blockIdx.x * blockDim.x + threadIdx.x;
    if (i < 32768) {
        unsigned short u = w1raw[i];
        if ((u & 0x7F80u) == 0x7F80u) atomicAdd(&flags[0], 1);
    }
}

__global__ void detect_edge_kernel(const int* __restrict__ ei, int* __restrict__ flags) {
    int i = blockIdx.x * blockDim.x + threadIdx.x;
    if (i < 2048) {
        if (ei[2 * i + 1] != 0) atomicAdd(&flags[1], 1);
    }
}

// ---------------- pack W1 into MFMA B-fragment order (bf16) ----------------
__global__ void pack_w1_kernel(const void* __restrict__ W1p, const int* __restrict__ flags,
                               unsigned short* __restrict__ pb) {
    int idx = blockIdx.x * 256 + threadIdx.x;   // 32768 total
    int j    = idx & 7;
    int lane = (idx >> 3) & 63;
    int ktnt = idx >> 9;            // nt*16 + kt
    int kt = ktnt & 15, nt = ktnt >> 4;
    int k = kt * 32 + (lane >> 4) * 8 + j;
    int n = nt * 16 + (lane & 15);
    unsigned short v;
    if (flags[0] > 0) v = f2bf(((const float*)W1p)[k * HIDDEN + n]);
    else              v = ((const unsigned short*)W1p)[k * HIDDEN + n];
    pb[idx] = v;
}

// ---------------- pack W2 (64x40) into B-frag order, N padded to 48 -------------
__global__ void pack_w2_kernel(const void* __restrict__ W2p, const int* __restrict__ flags,
                               unsigned short* __restrict__ pb2) {
    int idx = blockIdx.x * 256 + threadIdx.x;   // 3072 total
    if (idx >= 3072) return;
    int j    = idx & 7;
    int lane = (idx >> 3) & 63;
    int ktnt = idx >> 9;            // nt*2 + kt
    int kt = ktnt & 1, nt = ktnt >> 1;
    int k = kt * 32 + (lane >> 4) * 8 + j;
    int n = nt * 16 + (lane & 15);
    unsigned short v = 0;
    if (n < N_CLASSES) {
        if (flags[0] > 0) v = f2bf(((const float*)W2p)[k * N_CLASSES + n]);
        else              v = ((const unsigned short*)W2p)[k * N_CLASSES + n];
    }
    pb2[idx] = v;
}

// ---------------- MLP: h0 = relu(x@W1+b1)@W2+b2, both layers MFMA --------------
// 64 nodes/block; each wave owns its own 16-node m-tile and loops all 4 W1
// n-tiles. Stores h0 (fp32) and y0 = dinv*h0 (fp16, packed 40-half rows).
__global__ __launch_bounds__(256) void mlp_kernel(
    const void* __restrict__ xp,
    const unsigned short* __restrict__ pb,    // packed W1 B-frags
    const unsigned short* __restrict__ pb2,   // packed W2 B-frags
    const void* __restrict__ b1p,
    const void* __restrict__ b2p,
    const int* __restrict__ flags,
    const float* __restrict__ dinv,
    float* __restrict__ h0,
    __half* __restrict__ y0)
{
    __shared__ unsigned short hsb[4][16 * HPITCH];   // per-wave h tile, 9 KB
    const int t    = threadIdx.x;
    const int wave = t >> 6;
    const int lane = t & 63;
    const int quad = lane >> 4;
    const int ml   = lane & 15;
    const int mbase = blockIdx.x * 64 + wave * 16;   // this wave's 16 nodes
    const int isf32 = flags[0] > 0;
    const bool valid = mbase < N_NODES;

    const bf16x8* pbv = (const bf16x8*)pb;
    f32x4 acc[4];
    #pragma unroll
    for (int nt = 0; nt < 4; ++nt) acc[nt] = (f32x4){0.f, 0.f, 0.f, 0.f};

    if (valid) {
        if (!isf32) {
            const unsigned short* xrow = (const unsigned short*)xp
                                       + (size_t)(mbase + ml) * N_FEAT + quad * 8;
            #pragma unroll
            for (int kt = 0; kt < 16; ++kt) {
                bf16x8 a = *(const bf16x8*)(xrow + kt * 32);
                #pragma unroll
                for (int nt = 0; nt < 4; ++nt)
                    acc[nt] = __builtin_amdgcn_mfma_f32_16x16x32_bf16(
                        a, pbv[(nt * 16 + kt) * 64 + lane], acc[nt], 0, 0, 0);
            }
        } else {
            const float* xf = (const float*)xp + (size_t)(mbase + ml) * N_FEAT + quad * 8;
            #pragma unroll
            for (int kt = 0; kt < 16; ++kt) {
                float4 lo = *(const float4*)(xf + kt * 32);
                float4 hi = *(const float4*)(xf + kt * 32 + 4);
                bf16x8 a;
                a[0] = (short)f2bf(lo.x); a[1] = (short)f2bf(lo.y);
                a[2] = (short)f2bf(lo.z); a[3] = (short)f2bf(lo.w);
                a[4] = (short)f2bf(hi.x); a[5] = (short)f2bf(hi.y);
                a[6] = (short)f2bf(hi.z); a[7] = (short)f2bf(hi.w);
                #pragma unroll
                for (int nt = 0; nt < 4; ++nt)
                    acc[nt] = __builtin_amdgcn_mfma_f32_16x16x32_bf16(
                        a, pbv[(nt * 16 + kt) * 64 + lane], acc[nt], 0, 0, 0);
            }
        }

        #pragma unroll
        for (int nt = 0; nt < 4; ++nt) {
            float b1v = isf32 ? ((const float*)b1p)[nt * 16 + ml]
                              : bf2f(((const unsigned short*)b1p)[nt * 16 + ml]);
            #pragma unroll
            for (int r = 0; r < 4; ++r)
                hsb[wave][(quad * 4 + r) * HPITCH + nt * 16 + ml] =
                    f2bf(fmaxf(acc[nt][r] + b1v, 0.0f));
        }
    }
    __syncthreads();

    if (valid) {
        const bf16x8* pb2v = (const bf16x8*)pb2;
        f32x4 acc2[3];
        #pragma unroll
        for (int n2 = 0; n2 < 3; ++n2) acc2[n2] = (f32x4){0.f, 0.f, 0.f, 0.f};
        #pragma unroll
        for (int kt = 0; kt < 2; ++kt) {
            bf16x8 a = *(const bf16x8*)(&hsb[wave][ml * HPITCH + kt * 32 + quad * 8]);
            #pragma unroll
            for (int n2 = 0; n2 < 3; ++n2)
                acc2[n2] = __builtin_amdgcn_mfma_f32_16x16x32_bf16(
                    a, pb2v[(n2 * 2 + kt) * 64 + lane], acc2[n2], 0, 0, 0);
        }
        #pragma unroll
        for (int n2 = 0; n2 < 3; ++n2) {
            int n = n2 * 16 + ml;
            if (n < N_CLASSES) {
                float b2v = isf32 ? ((const float*)b2p)[n]
                                  : bf2f(((const unsigned short*)b2p)[n]);
                #pragma unroll
                for (int r = 0; r < 4; ++r) {
                    int node = mbase + quad * 4 + r;
                    float v = acc2[n2][r] + b2v;
                    h0[(size_t)node * N_CLASSES + n] = v;
                    y0[(size_t)node * 40 + n] = __float2half(v * dinv[node]);
                }
            }
        }
    }
}

// zero the pad rows (index N_NODES) of both ping-pong y buffers; pad-row gathers
// in phase_kernel contribute exactly 0.
__global__ void zero_pad_kernel(__half* __restrict__ a, __half* __restrict__ b) {
    int t = threadIdx.x;
    __half z = __float2half(0.0f);
    if (t < 48)             a[N40 + t] = z;
    else if (t < 96)        b[N40 + (t - 48)] = z;
}

// ---------------- Pass A: LDS-staged (dstwin 8 x srcphase 4) partition ----------
// Per-edge appends go to 32 LDS buckets (LDS atomics); one global cursor atomic
// per (block,bucket) + a coalesced tail burst. Overflow (adversarial only) ->
// ovf list. No per-edge global atomics anywhere.
__global__ __launch_bounds__(256) void partition_kernel(
    const int* __restrict__ ei, const int* __restrict__ flags,
    unsigned int* __restrict__ sub,
    int* __restrict__ cur, int2* __restrict__ ovf, int E)
{
    __shared__ unsigned buf[32][CAP];
    __shared__ int cnt_lds[32];
    __shared__ unsigned base_s[32];

    const int i64f = flags[1] == 0;
    const int per  = (E + PARTB - 1) / PARTB;
    const int e0   = blockIdx.x * per;
    const int e1   = min(e0 + per, E);

    if (threadIdx.x < 32) cnt_lds[threadIdx.x] = 0;
    __syncthreads();

    for (int e = e0 + threadIdx.x; e < e1; e += 256) {
        int c = i64f ? __builtin_nontemporal_load(ei + 2 * E + 2 * e)
                     : __builtin_nontemporal_load(ei + E + e);
        int r = i64f ? __builtin_nontemporal_load(ei + 2 * e)
                     : __builtin_nontemporal_load(ei + e);
        int wd = c / WIN;
        int sp = r / SRCWIN;
        int b  = wd * 4 + sp;
        unsigned pk = (unsigned)r | ((unsigned)(c - wd * WIN) << 17);
        int slot = atomicAdd(&cnt_lds[b], 1);
        if (slot < CAP) buf[b][slot] = pk;
        else { int op = atomicAdd(cur + 32, 1); ovf[op] = make_int2(r, c); }
    }
    __syncthreads();

    const int g  = threadIdx.x >> 3;      // bucket handled by this 8-lane group
    const int l8 = threadIdx.x & 7;
    const int n  = min(cnt_lds[g], CAP);
    if (l8 == 0 && n > 0) base_s[g] = (unsigned)atomicAdd(&cur[g], n);
    __syncthreads();
    if (n > 0) {
        unsigned base = base_s[g];
        unsigned bslot = (unsigned)g * SUBCAP;
        for (int i = l8; i < n; i += 8) {
            unsigned p = base + (unsigned)i;
            unsigned pk = buf[g][i];
            if (p < SUBCAP) sub[bslot + p] = pk;
            else {
                int op = atomicAdd(cur + 32, 1);
                ovf[op] = make_int2((int)(pk & 0x1FFFFu),
                                    (g >> 2) * WIN + (int)(pk >> 17));
            }
        }
    }
}

// ---------------- Pass B: per-sub-bucket LDS histogram (degrees, no atomics) ----
__global__ __launch_bounds__(1024) void hist_kernel(
    const unsigned int* __restrict__ sub, const int* __restrict__ cur,
    const int2* __restrict__ ovf, int* __restrict__ hists)
{
    __shared__ int h[WIN];   // 50 KB
    const int w = blockIdx.x & 7;
    const int s = blockIdx.x >> 3;          // 0..3
    const int b = w * 4 + s;
    for (int off = threadIdx.x; off < WIN; off += 1024) h[off] = 0;
    __syncthreads();
    int n = min(cur[b], SUBCAP);
    const unsigned int* sp = sub + (size_t)b * SUBCAP;
    for (int i = threadIdx.x; i < n; i += 1024)
        atomicAdd(&h[sp[i] >> 17], 1);
    if (s == 3) {
        int ov = cur[32];
        for (int i = threadIdx.x; i < ov; i += 1024) {
            int2 rc = ovf[i];
            int ww = rc.y / WIN;
            if (ww == w) atomicAdd(&h[rc.y - ww * WIN], 1);
        }
    }
    __syncthreads();
    for (int off = threadIdx.x; off < WIN; off += 1024)
        hists[(size_t)b * WIN + off] = h[off];
}

// ---------------- degree -> cnt + dinv (no atomics) ----------------
__global__ void cnt_kernel(const int* __restrict__ hists, int* __restrict__ cnt,
                           float* __restrict__ dinv) {
    int i = blockIdx.x * 256 + threadIdx.x;
    if (i >= N_NODES) return;
    int w = i / WIN, off = i - w * WIN;
    int c = 0;
    #pragma unroll
    for (int x = 0; x < 4; ++x) c += hists[(size_t)(w * 4 + x) * WIN + off];
    cnt[i] = c;
    dinv[i] = rsqrtf((float)c + 1.0f);  // +1 self-loop
}

// shuffle-based exclusive scan
__global__ __launch_bounds__(1024) void scan_kernel(
    const int* __restrict__ cnt, int* __restrict__ rptr, int E)
{
    __shared__ int wsum[16];
    __shared__ int carry_s, tiletot_s;
    const int t = threadIdx.x, wave = t >> 6, lane = t & 63;
    if (t == 0) carry_s = 0;
    __syncthreads();
    for (int base = 0; base < N_NODES; base += 4096) {
        int i0 = base + t * 4;
        int v0 = (i0 + 0 < N_NODES) ? cnt[i0 + 0] : 0;
        int v1 = (i0 + 1 < N_NODES) ? cnt[i0 + 1] : 0;
        int v2 = (i0 + 2 < N_NODES) ? cnt[i0 + 2] : 0;
        int v3 = (i0 + 3 < N_NODES) ? cnt[i0 + 3] : 0;
        int tl = v0 + v1 + v2 + v3;
        int sc = tl;
        #pragma unroll
        for (int off = 1; off < 64; off <<= 1) {
            int u = __shfl_up(sc, off, 64);
            if (lane >= off) sc += u;
        }
        if (lane == 63) wsum[wave] = sc;
        int wexcl = sc - tl;
        __syncthreads();
        if (wave == 0) {
            int wv = (lane < 16) ? wsum[lane] : 0;
            int ws = wv;
            #pragma unroll
            for (int off = 1; off < 16; off <<= 1) {
                int u = __shfl_up(ws, off, 64);
                if (lane >= off) ws += u;
            }
            if (lane < 16) wsum[lane] = ws - wv;   // exclusive
            if (lane == 15) tiletot_s = ws;        // inclusive tile total
        }
        __syncthreads();
        int P  = carry_s + wsum[wave] + wexcl;
        if (i0 + 0 < N_NODES) rptr[i0 + 0] = P;
        if (i0 + 1 < N_NODES) rptr[i0 + 1] = P + v0;
        if (i0 + 2 < N_NODES) rptr[i0 + 2] = P + v0 + v1;
        if (i0 + 3 < N_NODES) rptr[i0 + 3] = P + v0 + v1 + v2;
        __syncthreads();
        if (t == 0) carry_s += tiletot_s;
        __syncthreads();
    }
    if (t == 0) rptr[N_NODES] = E;
}

// ---------------- Pass C: race-free window-local scatter + soff emit ----------
// Block (w,s): LDS cursors = rptr[node] + prefix over earlier phases' hists ->
// every (node, phase) owns a disjoint srcidx range, segments ordered by phase.
// The cursor bases ARE the per-(node,phase) segment starts -> written to soff.
// ovf drained by (w,3) (lands inside segment 3; breaks phase-locality for those
// edges only — perf-irrelevant, correctness preserved).
__global__ __launch_bounds__(1024) void scatter_kernel(
    const unsigned int* __restrict__ sub, const int* __restrict__ cur,
    const int* __restrict__ hists, const int2* __restrict__ ovf,
    const int* __restrict__ rptr, int* __restrict__ srcidx, int* __restrict__ soff)
{
    __shared__ int curs[WIN];   // 50 KB
    const int w = blockIdx.x & 7;
    const int s = blockIdx.x >> 3;          // 0..3
    const int b = w * 4 + s;
    for (int off = threadIdx.x; off < WIN; off += 1024) {
        int node = w * WIN + off;
        int base = rptr[node];
        for (int x = 0; x < s; ++x)
            base += hists[(size_t)(w * 4 + x) * WIN + off];
        curs[off] = base;
        soff[node * 4 + s] = base;
    }
    __syncthreads();
    int n = min(cur[b], SUBCAP);
    const unsigned int* sp = sub + (size_t)b * SUBCAP;
    for (int i = threadIdx.x; i < n; i += 1024) {
        unsigned pk = sp[i];
        int slot = atomicAdd(&curs[pk >> 17], 1);
        srcidx[slot] = (int)(pk & 0x1FFFFu);
    }
    if (s == 3) {
        int ov = cur[32];
        for (int i = threadIdx.x; i < ov; i += 1024) {
            int2 rc = ovf[i];
            int ww = rc.y / WIN;
            if (ww == w) {
                int slot = atomicAdd(&curs[rc.y - ww * WIN], 1);
                srcidx[slot] = rc.x;
            }
        }
    }
}

// ---------------- propagation, phase pass: partial[p][node] = sum over segment p --
// Block bid: phase p = bid&3, nodes = (bid>>2)*16 .. +16. All gathers of a
// phase-p block hit src window p only (2 MB packed rows -> L2-resident on the
// hosting XCD; bid&7 round-robin puts one phase per XCD). Partials fp32
// (associativity-only change vs monolithic accumulation). Nontemporal partial
// stores keep the streaming writes from evicting the gather window.
__global__ __launch_bounds__(256) void phase_kernel(
    const __half* __restrict__ yin, const int* __restrict__ soff,
    const int* __restrict__ rptr, const int* __restrict__ srcidx,
    float* __restrict__ partial)
{
    const int p    = blockIdx.x & 3;
    const int nb   = blockIdx.x >> 2;
    const int wave = threadIdx.x >> 6;
    const int lane = threadIdx.x & 63;
    const int g    = lane >> 4;        // node subgroup 0..3
    const int l    = lane & 15;
    const int node = nb * 16 + wave * 4 + g;
    const int c0   = l * 4;
    const int offr = (l < 10) ? l * 4 : 0;   // halves offset in 40-half row

    const int start = soff[node * 4 + p];
    const int end   = (p < 3) ? soff[node * 4 + p + 1] : rptr[node + 1];
    int nch = (end - start + 15) >> 4;
    int m1    = max(nch, __shfl_xor(nch, 16, 64));
    int maxch = max(m1,  __shfl_xor(m1, 32, 64));

    float a0 = 0.f, a1 = 0.f, a2 = 0.f, a3 = 0.f;
    float b0 = 0.f, b1 = 0.f, b2 = 0.f, b3 = 0.f;

    for (int ch = 0; ch < maxch; ++ch) {
        int idx = start + ch * 16 + l;
        int sw  = (idx < end) ? srcidx[idx] : N_NODES;   // pad row => +0

        #pragma unroll
        for (int i = 0; i < 16; i += 2) {
            int s0 = __shfl(sw, (g << 4) + i,     64);
            int s1 = __shfl(sw, (g << 4) + i + 1, 64);
            uint2 z0 = *(const uint2*)(yin + (size_t)s0 * 40 + offr);
            uint2 z1 = *(const uint2*)(yin + (size_t)s1 * 40 + offr);
            const __half2* p0 = (const __half2*)&z0;
            const __half2* p1 = (const __half2*)&z1;
            float2 f00 = __half22float2(p0[0]);
            float2 f01 = __half22float2(p0[1]);
            float2 f10 = __half22float2(p1[0]);
            float2 f11 = __half22float2(p1[1]);
            a0 += f00.x; a1 += f00.y; a2 += f01.x; a3 += f01.y;
            b0 += f10.x; b1 += f10.y; b2 += f11.x; b3 += f11.y;
        }
    }

    if (c0 < N_CLASSES) {
        f32x4 o;
        o[0] = a0 + b0; o[1] = a1 + b1; o[2] = a2 + b2; o[3] = a3 + b3;
        f32x4* dst = (f32x4*)(partial + (size_t)p * N40 + (size_t)node * 40 + c0);
        __builtin_nontemporal_store(o, dst);
    }
}

// ---------------- propagation, reduce pass ----------------
// y_new = dinv * ( a*h0 + (1-a)*dinv*( sum_p partial[p] + y_self ) )
__global__ __launch_bounds__(256) void reduce_kernel(
    const float* __restrict__ partial, const __half* __restrict__ yin,
    const float* __restrict__ h0, const float* __restrict__ dinv,
    __half* __restrict__ yout)
{
    const int wave = threadIdx.x >> 6;
    const int lane = threadIdx.x & 63;
    const int g    = lane >> 4;
    const int l    = lane & 15;
    const int node = blockIdx.x * 16 + wave * 4 + g;
    const int c0   = l * 4;
    if (c0 >= N_CLASSES) return;

    float sx = 0.f, sy = 0.f, sz = 0.f, sw = 0.f;
    #pragma unroll
    for (int p = 0; p < NPH; ++p) {
        f32x4 v = *(const f32x4*)(partial + (size_t)p * N40 + (size_t)node * 40 + c0);
        sx += v[0]; sy += v[1]; sz += v[2]; sw += v[3];
    }
    uint2 ys = *(const uint2*)(yin + (size_t)node * 40 + c0);
    f32x4 h = *(const f32x4*)(h0 + (size_t)node * 40 + c0);
    float di = dinv[node];
    const __half2* ps = (const __half2*)&ys;
    float2 s01 = __half22float2(ps[0]);
    float2 s23 = __half22float2(ps[1]);
    float kk = (1.0f - ALPHA) * di;
    float o0 = ALPHA * h[0] + kk * (sx + s01.x);
    float o1 = ALPHA * h[1] + kk * (sy + s01.y);
    float o2 = ALPHA * h[2] + kk * (sz + s23.x);
    float o3 = ALPHA * h[3] + kk * (sw + s23.y);
    __half2 q01 = __floats2half2_rn(di * o0, di * o1);
    __half2 q23 = __floats2half2_rn(di * o2, di * o3);
    uint2 st;
    st.x = *(unsigned int*)&q01;
    st.y = *(unsigned int*)&q23;
    *(uint2*)(yout + (size_t)node * 40 + c0) = st;
}

// ---------------- log_softmax + store (fp32 or bf16 per flags[0]) ----------------
__global__ __launch_bounds__(256) void lsm_kernel(
    const __half* __restrict__ y, const float* __restrict__ dinv,
    const int* __restrict__ flags, void* __restrict__ outp)
{
    const int wave = threadIdx.x >> 6;
    const int lane = threadIdx.x & 63;
    const int node = blockIdx.x * 4 + wave;
    const int isf32 = flags[0] > 0;

    float di = dinv[node];
    float v = (lane < N_CLASSES)
            ? __half2float(y[(size_t)node * 40 + lane]) / di : -1e30f;
    float m = v;
    #pragma unroll
    for (int o = 32; o; o >>= 1) m = fmaxf(m, __shfl_xor(m, o, 64));
    float e = (lane < N_CLASSES) ? expf(v - m) : 0.0f;
    float s = e;
    #pragma unroll
    for (int o = 32; o; o >>= 1) s += __shfl_xor(s, o, 64);
    float ls = logf(s);
    if (lane < N_CLASSES) {
        float r = v - m - ls;
        size_t idx = (size_t)node * N_CLASSES + lane;
        if (isf32) ((float*)outp)[idx] = r;
        else       ((__hip_bfloat16*)outp)[idx] = __float2bfloat16(r);
    }
}

extern "C" void kernel_launch(void* const* d_in, const int* in_sizes, int n_in,
                              void* d_out, int out_size, void* d_ws, size_t ws_size,
                              hipStream_t stream)
{
    const void* x  = d_in[0];
    const void* W1 = d_in[1];
    const void* b1 = d_in[2];
    const void* W2 = d_in[3];
    const void* b2 = d_in[4];
    const int* ei = (const int*)d_in[5];
    const int E = in_sizes[5] / 2;

    // workspace carve-up (256B aligned)
    char* ws = (char*)d_ws;
    size_t off = 0;
    auto carve = [&](size_t bytes) -> void* {
        void* p = ws + off;
        off = (off + bytes + 255) & ~(size_t)255;
        return p;
    };
    float*  h0    = (float*) carve((size_t)N_NODES * N_CLASSES * 4);
    __half* yA    = (__half*)carve((N40 + 64) * 2);
    __half* yB    = (__half*)carve((N40 + 64) * 2);
    float*  partial = (float*)carve((size_t)NPH * N40 * 4);             // 64 MB
    int*    cnt   = (int*)   carve((size_t)N_NODES * 4);
    float*  dinv  = (float*) carve((size_t)N_NODES * 4);
    int*    rptr  = (int*)   carve((size_t)(N_NODES + 1) * 4);
    int*    soff  = (int*)   carve((size_t)N_NODES * 4 * 4);            // [N][4]
    int*    srcidx= (int*)   carve((size_t)E * 4);
    unsigned int* sub = (unsigned int*)carve((size_t)32 * SUBCAP * 4);  // 16.8 MB
    int*    hists = (int*)   carve((size_t)32 * WIN * 4);               // 1.6 MB
    int2*   ovf   = (int2*)  carve((size_t)E * 8);                      // 25.6 MB
    int*    cur   = (int*)   carve(33 * sizeof(int));
    unsigned short* pb  = (unsigned short*)carve(32768 * 2);
    unsigned short* pb2 = (unsigned short*)carve(3072 * 2);
    int*    flags = (int*)   carve(2 * sizeof(int));
    (void)ws_size; (void)n_in; (void)out_size;

    const int nodeBlocks  = N_NODES / 4;            // 25000
    const int mlpBlocks   = (N_NODES + 63) / 64;    // 1563
    const int nodeBlocks16= N_NODES / 16;           // 6250
    const int phaseBlocks = nodeBlocks16 * NPH;     // 25000
    const int cntBlocks   = (N_NODES + 255) / 256;

    // dtype detection + weight packing
    zero_cur_kernel<<<1, 64, 0, stream>>>(cur, flags);
    detect_float_kernel<<<128, 256, 0, stream>>>((const unsigned short*)W1, flags);
    detect_edge_kernel<<<8, 256, 0, stream>>>(ei, flags);
    pack_w1_kernel<<<128, 256, 0, stream>>>(W1, flags, pb);
    pack_w2_kernel<<<12, 256, 0, stream>>>(W2, flags, pb2);

    // CSR build: partition -> hist -> cnt/dinv -> scan -> scatter(+soff)
    partition_kernel<<<PARTB, 256, 0, stream>>>(ei, flags, sub, cur, ovf, E);
    hist_kernel<<<32, 1024, 0, stream>>>(sub, cur, ovf, hists);
    cnt_kernel<<<cntBlocks, 256, 0, stream>>>(hists, cnt, dinv);
    scan_kernel<<<1, 1024, 0, stream>>>(cnt, rptr, E);
    scatter_kernel<<<32, 1024, 0, stream>>>(sub, cur, hists, ovf, rptr, srcidx, soff);
    zero_pad_kernel<<<1, 128, 0, stream>>>(yA, yB);

    // MLP (both layers MFMA); stores h0 fp32 and y0 = dinv*h0 fp16 packed
    mlp_kernel<<<mlpBlocks, 256, 0, stream>>>(x, pb, pb2, b1, b2, flags, dinv, h0, yA);

    // K propagation steps: phase pass (L2-captured gathers) + reduce pass
    const __half* yin = yA;
    __half* yout = yB;
    const __half* ylast = yA;
    for (int it = 0; it < KITER; ++it) {
        phase_kernel<<<phaseBlocks, 256, 0, stream>>>(yin, soff, rptr, srcidx, partial);
        reduce_kernel<<<nodeBlocks16, 256, 0, stream>>>(partial, yin, h0, dinv, yout);
        ylast = yout;
        yin = yout;
        yout = (yout == yB) ? yA : yB;
    }

    lsm_kernel<<<nodeBlocks, 256, 0, stream>>>(ylast, dinv, flags, d_out);
}

// Round 10
// 1049.213 us; speedup vs baseline: 1.2176x; 1.2176x over previous
//
#include <hip/hip_runtime.h>
#include <hip/hip_bf16.h>
#include <hip/hip_fp16.h>

#define N_NODES   100000
#define N_FEAT    512
#define HIDDEN    64
#define N_CLASSES 40
#define KITER     10
#define ALPHA     0.1f
#define HPITCH    72      // LDS h pitch in halves (144 B) to break bank conflicts
#define NXCD      8
#define WIN       (N_NODES / NXCD)    // 12500 dst nodes per window
#define NSB       4                   // src sub-buckets per window (for scatter parallelism)
#define SRCWIN    (N_NODES / NSB)
#define SUBCAP    131072              // per-(dstwin,srcsb) cap (exp. 100K)
#define PARTB     2048                // partition blocks
#define CAP       128                 // LDS bucket capacity per (dstwin,srcsb) (exp. 49)

typedef __attribute__((ext_vector_type(8))) short bf16x8;
typedef __attribute__((ext_vector_type(4))) float f32x4;

__device__ __forceinline__ float bf2f(unsigned short u) {
    union { unsigned int i; float f; } c;
    c.i = ((unsigned int)u) << 16;
    return c.f;
}
__device__ __forceinline__ unsigned short f2bf(float f) {
    union { float f; unsigned int u; } c; c.f = f;
    unsigned int r = c.u + 0x7FFFu + ((c.u >> 16) & 1u);   // RNE
    return (unsigned short)(r >> 16);
}

// ---------------- setup / dtype detection ----------------
__global__ void zero_cur_kernel(int* __restrict__ cur, int* __restrict__ flags) {
    int t = threadIdx.x;
    if (t < 33) cur[t] = 0;    // 32 sub-bucket cursors + 1 overflow cursor
    if (t >= 33 && t < 35) flags[t - 33] = 0;
}

__global__ void detect_float_kernel(const unsigned short* __restrict__ w1raw,
                                    int* __restrict__ flags) {
    int i = blockIdx.x * blockDim.x + threadIdx.x;
    if (i < 32768) {
        unsigned short u = w1raw[i];
        if ((u & 0x7F80u) == 0x7F80u) atomicAdd(&flags[0], 1);
    }
}

__global__ void detect_edge_kernel(const int* __restrict__ ei, int* __restrict__ flags) {
    int i = blockIdx.x * blockDim.x + threadIdx.x;
    if (i < 2048) {
        if (ei[2 * i + 1] != 0) atomicAdd(&flags[1], 1);
    }
}

// ---------------- pack W1 into MFMA B-fragment order (bf16) ----------------
__global__ void pack_w1_kernel(const void* __restrict__ W1p, const int* __restrict__ flags,
                               unsigned short* __restrict__ pb) {
    int idx = blockIdx.x * 256 + threadIdx.x;   // 32768 total
    int j    = idx & 7;
    int lane = (idx >> 3) & 63;
    int ktnt = idx >> 9;            // nt*16 + kt
    int kt = ktnt & 15, nt = ktnt >> 4;
    int k = kt * 32 + (lane >> 4) * 8 + j;
    int n = nt * 16 + (lane & 15);
    unsigned short v;
    if (flags[0] > 0) v = f2bf(((const float*)W1p)[k * HIDDEN + n]);
    else              v = ((const unsigned short*)W1p)[k * HIDDEN + n];
    pb[idx] = v;
}

// ---------------- pack W2 (64x40) into B-frag order, N padded to 48 -------------
__global__ void pack_w2_kernel(const void* __restrict__ W2p, const int* __restrict__ flags,
                               unsigned short* __restrict__ pb2) {
    int idx = blockIdx.x * 256 + threadIdx.x;   // 3072 total
    if (idx >= 3072) return;
    int j    = idx & 7;
    int lane = (idx >> 3) & 63;
    int ktnt = idx >> 9;            // nt*2 + kt
    int kt = ktnt & 1, nt = ktnt >> 1;
    int k = kt * 32 + (lane >> 4) * 8 + j;
    int n = nt * 16 + (lane & 15);
    unsigned short v = 0;
    if (n < N_CLASSES) {
        if (flags[0] > 0) v = f2bf(((const float*)W2p)[k * N_CLASSES + n]);
        else              v = ((const unsigned short*)W2p)[k * N_CLASSES + n];
    }
    pb2[idx] = v;
}

// ---------------- MLP: h0 = relu(x@W1+b1)@W2+b2, both layers MFMA --------------
// 64 nodes/block; each wave owns its own 16-node m-tile and loops all 4 W1
// n-tiles. Stores h0 (fp32) and y0 = dinv*h0 (fp16, ZP=64 rows: one 128-B
// granule per row -> single-granule random gathers in prop).
__global__ __launch_bounds__(256) void mlp_kernel(
    const void* __restrict__ xp,
    const unsigned short* __restrict__ pb,    // packed W1 B-frags
    const unsigned short* __restrict__ pb2,   // packed W2 B-frags
    const void* __restrict__ b1p,
    const void* __restrict__ b2p,
    const int* __restrict__ flags,
    const float* __restrict__ dinv,
    float* __restrict__ h0,
    __half* __restrict__ y0)
{
    __shared__ unsigned short hsb[4][16 * HPITCH];   // per-wave h tile, 9 KB
    const int t    = threadIdx.x;
    const int wave = t >> 6;
    const int lane = t & 63;
    const int quad = lane >> 4;
    const int ml   = lane & 15;
    const int mbase = blockIdx.x * 64 + wave * 16;   // this wave's 16 nodes
    const int isf32 = flags[0] > 0;
    const bool valid = mbase < N_NODES;

    const bf16x8* pbv = (const bf16x8*)pb;
    f32x4 acc[4];
    #pragma unroll
    for (int nt = 0; nt < 4; ++nt) acc[nt] = (f32x4){0.f, 0.f, 0.f, 0.f};

    if (valid) {
        if (!isf32) {
            const unsigned short* xrow = (const unsigned short*)xp
                                       + (size_t)(mbase + ml) * N_FEAT + quad * 8;
            #pragma unroll
            for (int kt = 0; kt < 16; ++kt) {
                bf16x8 a = *(const bf16x8*)(xrow + kt * 32);
                #pragma unroll
                for (int nt = 0; nt < 4; ++nt)
                    acc[nt] = __builtin_amdgcn_mfma_f32_16x16x32_bf16(
                        a, pbv[(nt * 16 + kt) * 64 + lane], acc[nt], 0, 0, 0);
            }
        } else {
            const float* xf = (const float*)xp + (size_t)(mbase + ml) * N_FEAT + quad * 8;
            #pragma unroll
            for (int kt = 0; kt < 16; ++kt) {
                float4 lo = *(const float4*)(xf + kt * 32);
                float4 hi = *(const float4*)(xf + kt * 32 + 4);
                bf16x8 a;
                a[0] = (short)f2bf(lo.x); a[1] = (short)f2bf(lo.y);
                a[2] = (short)f2bf(lo.z); a[3] = (short)f2bf(lo.w);
                a[4] = (short)f2bf(hi.x); a[5] = (short)f2bf(hi.y);
                a[6] = (short)f2bf(hi.z); a[7] = (short)f2bf(hi.w);
                #pragma unroll
                for (int nt = 0; nt < 4; ++nt)
                    acc[nt] = __builtin_amdgcn_mfma_f32_16x16x32_bf16(
                        a, pbv[(nt * 16 + kt) * 64 + lane], acc[nt], 0, 0, 0);
            }
        }

        #pragma unroll
        for (int nt = 0; nt < 4; ++nt) {
            float b1v = isf32 ? ((const float*)b1p)[nt * 16 + ml]
                              : bf2f(((const unsigned short*)b1p)[nt * 16 + ml]);
            #pragma unroll
            for (int r = 0; r < 4; ++r)
                hsb[wave][(quad * 4 + r) * HPITCH + nt * 16 + ml] =
                    f2bf(fmaxf(acc[nt][r] + b1v, 0.0f));
        }
    }
    __syncthreads();

    if (valid) {
        const bf16x8* pb2v = (const bf16x8*)pb2;
        f32x4 acc2[3];
        #pragma unroll
        for (int n2 = 0; n2 < 3; ++n2) acc2[n2] = (f32x4){0.f, 0.f, 0.f, 0.f};
        #pragma unroll
        for (int kt = 0; kt < 2; ++kt) {
            bf16x8 a = *(const bf16x8*)(&hsb[wave][ml * HPITCH + kt * 32 + quad * 8]);
            #pragma unroll
            for (int n2 = 0; n2 < 3; ++n2)
                acc2[n2] = __builtin_amdgcn_mfma_f32_16x16x32_bf16(
                    a, pb2v[(n2 * 2 + kt) * 64 + lane], acc2[n2], 0, 0, 0);
        }
        #pragma unroll
        for (int n2 = 0; n2 < 3; ++n2) {
            int n = n2 * 16 + ml;
            if (n < N_CLASSES) {
                float b2v = isf32 ? ((const float*)b2p)[n]
                                  : bf2f(((const unsigned short*)b2p)[n]);
                #pragma unroll
                for (int r = 0; r < 4; ++r) {
                    int node = mbase + quad * 4 + r;
                    float v = acc2[n2][r] + b2v;
                    h0[(size_t)node * N_CLASSES + n] = v;
                    y0[((size_t)node << 6) + n] = __float2half(v * dinv[node]);
                }
            }
        }
    }
}

// zero the pad rows (index N_NODES) of both ping-pong y buffers; pad-row gathers
// in prop contribute exactly 0.
__global__ void zero_pad_kernel(__half* __restrict__ a, __half* __restrict__ b) {
    int t = threadIdx.x;
    __half z = __float2half(0.0f);
    if (t < 64)             a[((size_t)N_NODES << 6) + t] = z;
    else if (t < 128)       b[((size_t)N_NODES << 6) + (t - 64)] = z;
}

// ---------------- Pass A: LDS-staged (dstwin 8 x srcsb 4) partition ----------
// Per-edge appends go to 32 LDS buckets (LDS atomics); one global cursor atomic
// per (block,bucket) + a coalesced tail burst. Overflow (adversarial only) ->
// ovf list. No per-edge global atomics anywhere.
__global__ __launch_bounds__(256) void partition_kernel(
    const int* __restrict__ ei, const int* __restrict__ flags,
    unsigned int* __restrict__ sub,
    int* __restrict__ cur, int2* __restrict__ ovf, int E)
{
    __shared__ unsigned buf[32][CAP];
    __shared__ int cnt_lds[32];
    __shared__ unsigned base_s[32];

    const int i64f = flags[1] == 0;
    const int per  = (E + PARTB - 1) / PARTB;
    const int e0   = blockIdx.x * per;
    const int e1   = min(e0 + per, E);

    if (threadIdx.x < 32) cnt_lds[threadIdx.x] = 0;
    __syncthreads();

    for (int e = e0 + threadIdx.x; e < e1; e += 256) {
        int c = i64f ? __builtin_nontemporal_load(ei + 2 * E + 2 * e)
                     : __builtin_nontemporal_load(ei + E + e);
        int r = i64f ? __builtin_nontemporal_load(ei + 2 * e)
                     : __builtin_nontemporal_load(ei + e);
        int wd = c / WIN;
        int sp = r / SRCWIN;
        int b  = wd * 4 + sp;
        unsigned pk = (unsigned)r | ((unsigned)(c - wd * WIN) << 17);
        int slot = atomicAdd(&cnt_lds[b], 1);
        if (slot < CAP) buf[b][slot] = pk;
        else { int op = atomicAdd(cur + 32, 1); ovf[op] = make_int2(r, c); }
    }
    __syncthreads();

    const int g  = threadIdx.x >> 3;      // bucket handled by this 8-lane group
    const int l8 = threadIdx.x & 7;
    const int n  = min(cnt_lds[g], CAP);
    if (l8 == 0 && n > 0) base_s[g] = (unsigned)atomicAdd(&cur[g], n);
    __syncthreads();
    if (n > 0) {
        unsigned base = base_s[g];
        unsigned bslot = (unsigned)g * SUBCAP;
        for (int i = l8; i < n; i += 8) {
            unsigned p = base + (unsigned)i;
            unsigned pk = buf[g][i];
            if (p < SUBCAP) sub[bslot + p] = pk;
            else {
                int op = atomicAdd(cur + 32, 1);
                ovf[op] = make_int2((int)(pk & 0x1FFFFu),
                                    (g >> 2) * WIN + (int)(pk >> 17));
            }
        }
    }
}

// ---------------- Pass B: per-sub-bucket LDS histogram (degrees, no atomics) ----
__global__ __launch_bounds__(1024) void hist_kernel(
    const unsigned int* __restrict__ sub, const int* __restrict__ cur,
    const int2* __restrict__ ovf, int* __restrict__ hists)
{
    __shared__ int h[WIN];   // 50 KB
    const int w = blockIdx.x & 7;
    const int s = blockIdx.x >> 3;          // 0..3
    const int b = w * 4 + s;
    for (int off = threadIdx.x; off < WIN; off += 1024) h[off] = 0;
    __syncthreads();
    int n = min(cur[b], SUBCAP);
    const unsigned int* sp = sub + (size_t)b * SUBCAP;
    for (int i = threadIdx.x; i < n; i += 1024)
        atomicAdd(&h[sp[i] >> 17], 1);
    if (s == 3) {
        int ov = cur[32];
        for (int i = threadIdx.x; i < ov; i += 1024) {
            int2 rc = ovf[i];
            int ww = rc.y / WIN;
            if (ww == w) atomicAdd(&h[rc.y - ww * WIN], 1);
        }
    }
    __syncthreads();
    for (int off = threadIdx.x; off < WIN; off += 1024)
        hists[(size_t)b * WIN + off] = h[off];
}

// ---------------- degree -> cnt + dinv (no atomics) ----------------
__global__ void cnt_kernel(const int* __restrict__ hists, int* __restrict__ cnt,
                           float* __restrict__ dinv) {
    int i = blockIdx.x * 256 + threadIdx.x;
    if (i >= N_NODES) return;
    int w = i / WIN, off = i - w * WIN;
    int c = 0;
    #pragma unroll
    for (int x = 0; x < 4; ++x) c += hists[(size_t)(w * 4 + x) * WIN + off];
    cnt[i] = c;
    dinv[i] = rsqrtf((float)c + 1.0f);  // +1 self-loop
}

// shuffle-based exclusive scan
__global__ __launch_bounds__(1024) void scan_kernel(
    const int* __restrict__ cnt, int* __restrict__ rptr, int E)
{
    __shared__ int wsum[16];
    __shared__ int carry_s, tiletot_s;
    const int t = threadIdx.x, wave = t >> 6, lane = t & 63;
    if (t == 0) carry_s = 0;
    __syncthreads();
    for (int base = 0; base < N_NODES; base += 4096) {
        int i0 = base + t * 4;
        int v0 = (i0 + 0 < N_NODES) ? cnt[i0 + 0] : 0;
        int v1 = (i0 + 1 < N_NODES) ? cnt[i0 + 1] : 0;
        int v2 = (i0 + 2 < N_NODES) ? cnt[i0 + 2] : 0;
        int v3 = (i0 + 3 < N_NODES) ? cnt[i0 + 3] : 0;
        int tl = v0 + v1 + v2 + v3;
        int sc = tl;
        #pragma unroll
        for (int off = 1; off < 64; off <<= 1) {
            int u = __shfl_up(sc, off, 64);
            if (lane >= off) sc += u;
        }
        if (lane == 63) wsum[wave] = sc;
        int wexcl = sc - tl;
        __syncthreads();
        if (wave == 0) {
            int wv = (lane < 16) ? wsum[lane] : 0;
            int ws = wv;
            #pragma unroll
            for (int off = 1; off < 16; off <<= 1) {
                int u = __shfl_up(ws, off, 64);
                if (lane >= off) ws += u;
            }
            if (lane < 16) wsum[lane] = ws - wv;   // exclusive
            if (lane == 15) tiletot_s = ws;        // inclusive tile total
        }
        __syncthreads();
        int P  = carry_s + wsum[wave] + wexcl;
        if (i0 + 0 < N_NODES) rptr[i0 + 0] = P;
        if (i0 + 1 < N_NODES) rptr[i0 + 1] = P + v0;
        if (i0 + 2 < N_NODES) rptr[i0 + 2] = P + v0 + v1;
        if (i0 + 3 < N_NODES) rptr[i0 + 3] = P + v0 + v1 + v2;
        __syncthreads();
        if (t == 0) carry_s += tiletot_s;
        __syncthreads();
    }
    if (t == 0) rptr[N_NODES] = E;
}

// ---------------- Pass C: race-free window-local scatter (no global atomics) ----
// Block (w,s): LDS cursors = rptr[node] + prefix over earlier sub-buckets' hists
// -> every (node, sub-bucket) owns a disjoint srcidx range. All writes to window
// w come from bid%8==w -> one coherent L2, full-line writebacks.
__global__ __launch_bounds__(1024) void scatter_kernel(
    const unsigned int* __restrict__ sub, const int* __restrict__ cur,
    const int* __restrict__ hists, const int2* __restrict__ ovf,
    const int* __restrict__ rptr, int* __restrict__ srcidx)
{
    __shared__ int curs[WIN];   // 50 KB
    const int w = blockIdx.x & 7;
    const int s = blockIdx.x >> 3;          // 0..3
    const int b = w * 4 + s;
    for (int off = threadIdx.x; off < WIN; off += 1024) {
        int node = w * WIN + off;
        int base = rptr[node];
        for (int x = 0; x < s; ++x)
            base += hists[(size_t)(w * 4 + x) * WIN + off];
        curs[off] = base;
    }
    __syncthreads();
    int n = min(cur[b], SUBCAP);
    const unsigned int* sp = sub + (size_t)b * SUBCAP;
    for (int i = threadIdx.x; i < n; i += 1024) {
        unsigned pk = sp[i];
        int slot = atomicAdd(&curs[pk >> 17], 1);
        srcidx[slot] = (int)(pk & 0x1FFFFu);
    }
    if (s == 3) {
        int ov = cur[32];
        for (int i = threadIdx.x; i < ov; i += 1024) {
            int2 rc = ovf[i];
            int ww = rc.y / WIN;
            if (ww == w) {
                int slot = atomicAdd(&curs[rc.y - ww * WIN], 1);
                srcidx[slot] = rc.x;
            }
        }
    }
}

// ---------------- propagation on rescaled state y = dinv*z (ZP=64 rows) --------
// y_new[c] = dinv[c] * ( a*h0[c] + (1-a)*dinv[c]*( sum_edges y[src] + y[c] ) )
// On the LAST step, z-space values are kept in registers and log_softmax is
// fused: max/sum across the 16-lane node group via __shfl_xor(width=16);
// lanes 10-15 contribute identities. Saves the lsm kernel + one y roundtrip
// and removes one fp16 quantization from the output path.
__global__ __launch_bounds__(256) void prop_kernel(
    const __half* __restrict__ zh, const float* __restrict__ h0,
    const float* __restrict__ dinv, const int* __restrict__ rptr,
    const int* __restrict__ srcidx, __half* __restrict__ zout,
    const int* __restrict__ flags, void* __restrict__ outp, int last)
{
    const int wave = threadIdx.x >> 6;
    const int lane = threadIdx.x & 63;
    const int g    = lane >> 4;        // node subgroup 0..3
    const int l    = lane & 15;        // lane within group
    const int node = blockIdx.x * 16 + wave * 4 + g;
    const int c0   = l * 4;            // first class handled by this lane

    const int beg = rptr[node];
    const int end = rptr[node + 1];
    int nch = (end - beg + 15) >> 4;
    int m1    = max(nch, __shfl_xor(nch, 16, 64));
    int maxch = max(m1,  __shfl_xor(m1, 32, 64));

    // issue long-latency per-node loads early
    float di = dinv[node];
    uint2 yself = *(const uint2*)(zh + ((size_t)node << 6) + c0);
    float h00 = 0.f, h01 = 0.f, h02 = 0.f, h03 = 0.f;
    if (c0 < N_CLASSES) {
        const float* hp = h0 + (size_t)node * N_CLASSES + c0;
        h00 = hp[0]; h01 = hp[1]; h02 = hp[2]; h03 = hp[3];
    }

    float a0 = 0.f, a1 = 0.f, a2 = 0.f, a3 = 0.f;
    float b0 = 0.f, b1 = 0.f, b2 = 0.f, b3 = 0.f;

    int idx0 = beg + l;
    int sw = (idx0 < end) ? srcidx[idx0] : N_NODES;   // pad row => +0

    for (int ch = 0; ch < maxch; ++ch) {
        // prefetch next chunk's srcidx before consuming this one
        int idxn = beg + (ch + 1) * 16 + l;
        int swn = (ch + 1 < maxch) ? ((idxn < end) ? srcidx[idxn] : N_NODES) : N_NODES;

        #pragma unroll
        for (int i = 0; i < 16; i += 2) {
            int s0 = __shfl(sw, (g << 4) + i,     64);
            int s1 = __shfl(sw, (g << 4) + i + 1, 64);
            uint2 z0 = *(const uint2*)(zh + ((size_t)s0 << 6) + c0);
            uint2 z1 = *(const uint2*)(zh + ((size_t)s1 << 6) + c0);
            const __half2* p0 = (const __half2*)&z0;
            const __half2* p1 = (const __half2*)&z1;
            float2 f00 = __half22float2(p0[0]);
            float2 f01 = __half22float2(p0[1]);
            float2 f10 = __half22float2(p1[0]);
            float2 f11 = __half22float2(p1[1]);
            a0 += f00.x; a1 += f00.y; a2 += f01.x; a3 += f01.y;
            b0 += f10.x; b1 += f10.y; b2 += f11.x; b3 += f11.y;
        }
        sw = swn;
    }

    // z-space outputs
    float o0 = 0.f, o1 = 0.f, o2 = 0.f, o3 = 0.f;
    if (c0 < N_CLASSES) {
        const __half2* ps = (const __half2*)&yself;
        float2 s01 = __half22float2(ps[0]);
        float2 s23 = __half22float2(ps[1]);
        float kk = (1.0f - ALPHA) * di;
        o0 = ALPHA * h00 + kk * (a0 + b0 + s01.x);
        o1 = ALPHA * h01 + kk * (a1 + b1 + s01.y);
        o2 = ALPHA * h02 + kk * (a2 + b2 + s23.x);
        o3 = ALPHA * h03 + kk * (a3 + b3 + s23.y);
    }

    if (!last) {
        if (c0 < N_CLASSES) {
            __half2 q01 = __floats2half2_rn(di * o0, di * o1);
            __half2 q23 = __floats2half2_rn(di * o2, di * o3);
            uint2 st;
            st.x = *(unsigned int*)&q01;
            st.y = *(unsigned int*)&q23;
            *(uint2*)(zout + ((size_t)node << 6) + c0) = st;
        }
    } else {
        // fused log_softmax over the 16-lane node group (10 active lanes)
        float mx = (c0 < N_CLASSES) ? fmaxf(fmaxf(o0, o1), fmaxf(o2, o3)) : -1e30f;
        #pragma unroll
        for (int msk = 1; msk < 16; msk <<= 1)
            mx = fmaxf(mx, __shfl_xor(mx, msk, 16));
        float es = (c0 < N_CLASSES)
                 ? (expf(o0 - mx) + expf(o1 - mx) + expf(o2 - mx) + expf(o3 - mx))
                 : 0.0f;
        #pragma unroll
        for (int msk = 1; msk < 16; msk <<= 1)
            es += __shfl_xor(es, msk, 16);
        float ls = logf(es);
        if (c0 < N_CLASSES) {
            size_t idx = (size_t)node * N_CLASSES + c0;
            float r0 = o0 - mx - ls, r1 = o1 - mx - ls;
            float r2 = o2 - mx - ls, r3 = o3 - mx - ls;
            if (flags[0] > 0) {
                float* op = (float*)outp;
                op[idx] = r0; op[idx + 1] = r1; op[idx + 2] = r2; op[idx + 3] = r3;
            } else {
                __hip_bfloat16* op = (__hip_bfloat16*)outp;
                op[idx]     = __float2bfloat16(r0);
                op[idx + 1] = __float2bfloat16(r1);
                op[idx + 2] = __float2bfloat16(r2);
                op[idx + 3] = __float2bfloat16(r3);
            }
        }
    }
}

extern "C" void kernel_launch(void* const* d_in, const int* in_sizes, int n_in,
                              void* d_out, int out_size, void* d_ws, size_t ws_size,
                              hipStream_t stream)
{
    const void* x  = d_in[0];
    const void* W1 = d_in[1];
    const void* b1 = d_in[2];
    const void* W2 = d_in[3];
    const void* b2 = d_in[4];
    const int* ei = (const int*)d_in[5];
    const int E = in_sizes[5] / 2;

    // workspace carve-up (256B aligned)
    char* ws = (char*)d_ws;
    size_t off = 0;
    auto carve = [&](size_t bytes) -> void* {
        void* p = ws + off;
        off = (off + bytes + 255) & ~(size_t)255;
        return p;
    };
    float*  h0    = (float*) carve((size_t)N_NODES * N_CLASSES * 4);
    __half* yA    = (__half*)carve(((size_t)(N_NODES + 1) << 6) * 2);
    __half* yB    = (__half*)carve(((size_t)(N_NODES + 1) << 6) * 2);
    int*    cnt   = (int*)   carve((size_t)N_NODES * 4);
    float*  dinv  = (float*) carve((size_t)N_NODES * 4);
    int*    rptr  = (int*)   carve((size_t)(N_NODES + 1) * 4);
    int*    srcidx= (int*)   carve((size_t)E * 4);
    unsigned int* sub = (unsigned int*)carve((size_t)32 * SUBCAP * 4);  // 16.8 MB
    int*    hists = (int*)   carve((size_t)32 * WIN * 4);               // 1.6 MB
    int2*   ovf   = (int2*)  carve((size_t)E * 8);                      // 25.6 MB
    int*    cur   = (int*)   carve(33 * sizeof(int));
    unsigned short* pb  = (unsigned short*)carve(32768 * 2);
    unsigned short* pb2 = (unsigned short*)carve(3072 * 2);
    int*    flags = (int*)   carve(2 * sizeof(int));
    (void)ws_size; (void)n_in; (void)out_size;

    const int mlpBlocks   = (N_NODES + 63) / 64;    // 1563
    const int propBlocks  = N_NODES / 16;           // 6250
    const int cntBlocks   = (N_NODES + 255) / 256;

    // dtype detection + weight packing
    zero_cur_kernel<<<1, 64, 0, stream>>>(cur, flags);
    detect_float_kernel<<<128, 256, 0, stream>>>((const unsigned short*)W1, flags);
    detect_edge_kernel<<<8, 256, 0, stream>>>(ei, flags);
    pack_w1_kernel<<<128, 256, 0, stream>>>(W1, flags, pb);
    pack_w2_kernel<<<12, 256, 0, stream>>>(W2, flags, pb2);

    // CSR build: partition -> hist -> cnt/dinv -> scan -> race-free scatter
    partition_kernel<<<PARTB, 256, 0, stream>>>(ei, flags, sub, cur, ovf, E);
    hist_kernel<<<32, 1024, 0, stream>>>(sub, cur, ovf, hists);
    cnt_kernel<<<cntBlocks, 256, 0, stream>>>(hists, cnt, dinv);
    scan_kernel<<<1, 1024, 0, stream>>>(cnt, rptr, E);
    scatter_kernel<<<32, 1024, 0, stream>>>(sub, cur, hists, ovf, rptr, srcidx);
    zero_pad_kernel<<<1, 128, 0, stream>>>(yA, yB);

    // MLP (both layers MFMA); stores h0 fp32 and y0 = dinv*h0 fp16 (ZP=64)
    mlp_kernel<<<mlpBlocks, 256, 0, stream>>>(x, pb, pb2, b1, b2, flags, dinv, h0, yA);

    // K propagation steps (ping-pong fp16); final step fuses log_softmax
    const __half* yin = yA;
    __half* yout = yB;
    for (int it = 0; it < KITER; ++it) {
        int last = (it == KITER - 1) ? 1 : 0;
        prop_kernel<<<propBlocks, 256, 0, stream>>>(yin, h0, dinv, rptr, srcidx,
                                                    yout, flags, d_out, last);
        yin = yout;
        yout = (yout == yB) ? yA : yB;
    }
}